// Round 6
// baseline (377.745 us; speedup 1.0000x reference)
//
#include <hip/hip_runtime.h>
#include <stdint.h>

#define SEQ 41
#define KG 8
#define MM 5
#define SITE 20
#define LROW 43   // xs row stride in f32: (43*4B) -> ~2-way LDS bank spread (free)

typedef float f32x4 __attribute__((ext_vector_type(4)));
typedef short bf16x8 __attribute__((ext_vector_type(8)));
typedef unsigned int u32x4 __attribute__((ext_vector_type(4)));

union FragU { u32x4 u; bf16x8 h; };

__device__ __forceinline__ unsigned short f2bf(float f) {
    union { float f; uint32_t u; } v; v.f = f;
    uint32_t u = v.u;
    u += 0x7fffu + ((u >> 16) & 1u);   // round-to-nearest-even
    return (unsigned short)(u >> 16);
}

// truncating pack {a.hi16, b.hi16} -> one dword of 2 bf16, single v_perm_b32
__device__ __forceinline__ uint32_t pk2(float a, float b) {
    union { float f; uint32_t u; } ua, ub; ua.f = a; ub.f = b;
    return __builtin_amdgcn_perm(ub.u, ua.u, 0x07060302u);
}

// exact-shape fast tanh: 1 - 2/(e^{2x}+1); correct limits at +/-inf
__device__ __forceinline__ float fast_tanh(float x) {
    float e = __builtin_amdgcn_exp2f(x * 2.8853900817779268f);  // e^{2x}
    return 1.0f - 2.0f * __builtin_amdgcn_rcpf(e + 1.0f);
}

// ---------------- Kernel 0: weight fragment precompute (runs once/call) ----
// Layout: wf_u16[f*512 + lane*8 + j], f=(k*2+ks)*3+mt; A[m=o][K=i]=w1d[(o*41+i)*3+k]
__global__ void k_wprep(const float* __restrict__ w1d, unsigned short* __restrict__ wf) {
    for (int p = threadIdx.x; p < 18 * 64; p += 256) {
        int f = p >> 6, lane = p & 63;
        int k = f / 6, ks = (f / 3) % 2, mt = f % 3;
        int o = mt * 16 + (lane & 15);
#pragma unroll
        for (int j = 0; j < 8; ++j) {
            int i = ks * 32 + (lane >> 4) * 8 + j;
            float v = (o < SEQ && i < SEQ) ? w1d[(o * SEQ + i) * 3 + k] : 0.0f;
            wf[(size_t)p * 8 + j] = f2bf(v);
        }
    }
}

__device__ __forceinline__ int wave_argmax(float v) {
    float m = v;
#pragma unroll
    for (int off = 32; off; off >>= 1) {
        float o = __shfl_xor(m, off);
        m = fmaxf(m, o);
    }
    unsigned long long bal = __ballot(v == m);
    return __ffsll((unsigned long long)bal) - 1;
}

// ---------------- Fused kernel: one block per batch ------------------------
// A: stage x[b] -> LDS xs (read x from HBM ONCE)
// B: wave0 = select; waves1-3 = conv1d MFMA (one 16-col tile each); wave1 asite
// C: conv2d from xs via ridx (no global gather)
__global__ __launch_bounds__(256) void k_fused(const float* __restrict__ att,
                                               const float* __restrict__ deg,
                                               const float* __restrict__ x,
                                               const bf16x8* __restrict__ wf,
                                               const float* __restrict__ b1d,
                                               const float* __restrict__ w2,
                                               const float* __restrict__ b2,
                                               float* __restrict__ o_bag,
                                               float* __restrict__ o_asite,
                                               float* __restrict__ o_site,
                                               float* __restrict__ o_idx) {
    __shared__ float xs[SEQ * LROW];
    __shared__ int ridx[KG * MM];
    const int tid = threadIdx.x;
    const int wid = tid >> 6;
    const int lane = tid & 63;
    const int b = blockIdx.x;
    const float* xb = x + (size_t)b * (SEQ * SEQ);

    // ---- phase A: stage x slab (coalesced) ----
    for (int t = tid; t < SEQ * SEQ; t += 256) {
        int r = t / SEQ, c = t - r * SEQ;
        xs[r * LROW + c] = xb[t];
    }
    __syncthreads();

    if (wid == 0) {
        // ---- select (register-only argmax cascades) ----
        float dv = (lane < SEQ) ? deg[(size_t)b * SEQ + lane] : -1e30f;
        const float* abase = att + (size_t)b * SEQ * SEQ;
        float* outp = o_idx + (size_t)b * (KG * MM);
        int bis[KG];
#pragma unroll
        for (int g = 0; g < KG; ++g) {
            int bi = wave_argmax(dv);
            if (lane == bi) dv = -1e30f;
            bis[g] = bi;
        }
        float rv[KG];  // all 8 row loads issued together (latency overlapped)
#pragma unroll
        for (int g = 0; g < KG; ++g)
            rv[g] = (lane < SEQ) ? abase[(size_t)bis[g] * SEQ + lane] : -1e30f;

        bool my_sel = (lane == SITE);
#pragma unroll
        for (int g = 0; g < KG; ++g) {
            float r = my_sel ? -1e30f : rv[g];
            unsigned long long grp = 0;
#pragma unroll
            for (int m = 0; m < MM; ++m) {
                int pi = wave_argmax(r);
                if (lane == pi) { r = -1e30f; my_sel = true; }
                grp |= 1ull << pi;
            }
            if (lane < MM) {
                unsigned long long gg = grp;
                for (int t = 0; t < lane; ++t) gg &= gg - 1;
                int v = __ffsll((unsigned long long)gg) - 1;
                outp[g * MM + lane] = (float)v;
                ridx[g * MM + lane] = v;
            }
        }
    } else {
        // ---- conv1d: this wave computes output cols h = nt*16 .. nt*16+15 ----
        const int nt = wid - 1;
        const int h16 = lane & 15;
        const int kgrp = lane >> 4;

        if (wid == 1 && lane < SEQ)
            o_asite[(size_t)b * SEQ + lane] = xs[SITE * LROW + lane];

        bf16x8 afr[18];
#pragma unroll
        for (int f = 0; f < 18; ++f) afr[f] = wf[f * 64 + lane];

        f32x4 acc[3];
#pragma unroll
        for (int a = 0; a < 3; ++a)
#pragma unroll
            for (int j = 0; j < 4; ++j) acc[a][j] = 0.0f;

#pragma unroll
        for (int kc = 0; kc < 3; ++kc) {
            int r = nt * 16 + h16 + kc - 1;
            bool ok = (r >= 0) && (r < SEQ);
            const float* rp = &xs[(ok ? r : 0) * LROW];
            // ks=0: cols kgrp*8..+7 (max 31 < 41, always valid)
            u32x4 p0;
            p0[0] = pk2(rp[kgrp * 8 + 0], rp[kgrp * 8 + 1]);
            p0[1] = pk2(rp[kgrp * 8 + 2], rp[kgrp * 8 + 3]);
            p0[2] = pk2(rp[kgrp * 8 + 4], rp[kgrp * 8 + 5]);
            p0[3] = pk2(rp[kgrp * 8 + 6], rp[kgrp * 8 + 7]);
            // ks=1: kgrp0 -> cols 32..39; kgrp1 -> col 40; else zeros
            u32x4 p1 = {0u, 0u, 0u, 0u};
            if (kgrp == 0) {
                p1[0] = pk2(rp[32], rp[33]); p1[1] = pk2(rp[34], rp[35]);
                p1[2] = pk2(rp[36], rp[37]); p1[3] = pk2(rp[38], rp[39]);
            } else if (kgrp == 1) {
                p1[0] = pk2(rp[40], 0.0f);
            }
            if (!ok) {
#pragma unroll
                for (int q = 0; q < 4; ++q) { p0[q] = 0u; p1[q] = 0u; }
            }
            FragU F0, F1; F0.u = p0; F1.u = p1;
#pragma unroll
            for (int mt = 0; mt < 3; ++mt)
                acc[mt] = __builtin_amdgcn_mfma_f32_16x16x32_bf16(
                    afr[(kc * 2 + 0) * 3 + mt], F0.h, acc[mt], 0, 0, 0);
#pragma unroll
            for (int mt = 0; mt < 3; ++mt)
                acc[mt] = __builtin_amdgcn_mfma_f32_16x16x32_bf16(
                    afr[(kc * 2 + 1) * 3 + mt], F1.h, acc[mt], 0, 0, 0);
        }

        // epilogue: +bias, double fast-tanh, predicated store
        int h = nt * 16 + h16;
        if (h < SEQ) {
            float* outb = o_site + (size_t)b * (SEQ * SEQ);
#pragma unroll
            for (int mt = 0; mt < 3; ++mt)
#pragma unroll
                for (int j = 0; j < 4; ++j) {
                    int o = mt * 16 + kgrp * 4 + j;
                    if (o < SEQ)
                        outb[o * SEQ + h] = fast_tanh(fast_tanh(acc[mt][j] + b1d[o]));
                }
        }
    }
    __syncthreads();

    // ---- phase C: conv2d straight from xs (w2 uniform -> scalar-pipe loads) ----
    if (tid < MM * SEQ) {
        int m = tid / SEQ, w = tid - (tid / SEQ) * SEQ;
        float acc2[KG];
#pragma unroll
        for (int o = 0; o < KG; ++o) acc2[o] = b2[o];
#pragma unroll
        for (int i = 0; i < KG; ++i)
#pragma unroll
            for (int kh = 0; kh < 3; ++kh) {
                int mm = m + kh - 1;
                if (mm >= 0 && mm < MM) {
                    int row = ridx[i * MM + mm];
                    const float* rp = &xs[row * LROW];
#pragma unroll
                    for (int kw = 0; kw < 3; ++kw) {
                        int c = w + kw - 1;
                        float cv = (c >= 0 && c < SEQ) ? rp[c] : 0.0f;
#pragma unroll
                        for (int o = 0; o < KG; ++o)
                            acc2[o] += cv * w2[((o * KG + i) * 3 + kh) * 3 + kw];
                    }
                }
            }
        size_t base = (size_t)b * (KG * MM * SEQ) + (size_t)m * SEQ + w;
#pragma unroll
        for (int o = 0; o < KG; ++o)
            o_bag[base + (size_t)o * (MM * SEQ)] = acc2[o];
    }
}

extern "C" void kernel_launch(void* const* d_in, const int* in_sizes, int n_in,
                              void* d_out, int out_size, void* d_ws, size_t ws_size,
                              hipStream_t stream) {
    const float* att = (const float*)d_in[0];
    const float* deg = (const float*)d_in[1];
    const float* x   = (const float*)d_in[2];
    const float* w1d = (const float*)d_in[3];
    const float* b1d = (const float*)d_in[4];
    const float* w2d = (const float*)d_in[5];
    const float* b2d = (const float*)d_in[6];
    const int B = in_sizes[1] / SEQ;  // degree is [B, SEQ]

    float* out = (float*)d_out;
    const size_t s_bag   = (size_t)B * KG * MM * SEQ;  // x_bag  [B,8,5,41]
    const size_t s_asite = (size_t)B * SEQ;            // Asite  [B,1,41]
    const size_t s_site  = (size_t)B * SEQ * SEQ;      // x_site [B,41,41]
    float* o_bag   = out;
    float* o_asite = out + s_bag;
    float* o_site  = out + s_bag + s_asite;
    float* o_idx   = out + s_bag + s_asite + s_site;   // index_all as f32 [B,8,5]

    k_wprep<<<1, 256, 0, stream>>>(w1d, (unsigned short*)d_ws);
    k_fused<<<B, 256, 0, stream>>>(att, deg, x, (const bf16x8*)d_ws, b1d, w2d, b2d,
                                   o_bag, o_asite, o_site, o_idx);
}

// Round 7
// 209.524 us; speedup vs baseline: 1.8029x; 1.8029x over previous
//
#include <hip/hip_runtime.h>
#include <stdint.h>

#define SEQ 41
#define KG 8
#define MM 5
#define SITE 20
#define ROWS 50   // LDS rows: row c = x row c-1; rows 0,42..49 zero
#define RST 72    // row stride in halfwords (144 B -> non-pow2 bank spread)

typedef float f32x4 __attribute__((ext_vector_type(4)));
typedef short bf16x8 __attribute__((ext_vector_type(8)));
typedef unsigned int u32x4 __attribute__((ext_vector_type(4)));

union FragU { u32x4 u; bf16x8 h; };

__device__ __forceinline__ unsigned short f2bf(float f) {
    union { float f; uint32_t u; } v; v.f = f;
    uint32_t u = v.u;
    u += 0x7fffu + ((u >> 16) & 1u);   // round-to-nearest-even
    return (unsigned short)(u >> 16);
}

// truncating pack {b.hi16, a.hi16} -> dword of 2 bf16 (hw0=a, hw1=b), 1 v_perm
__device__ __forceinline__ uint32_t pk2(float a, float b) {
    union { float f; uint32_t u; } ua, ub; ua.f = a; ub.f = b;
    return __builtin_amdgcn_perm(ub.u, ua.u, 0x07060302u);
}

// unaligned-safe 16B load (row bases are only 4B-aligned)
__device__ __forceinline__ f32x4 ld4u(const float* p) {
    f32x4 v; __builtin_memcpy(&v, p, 16); return v;
}

// exact-shape fast tanh: 1 - 2/(e^{2x}+1); correct limits at +/-inf
__device__ __forceinline__ float fast_tanh(float x) {
    float e = __builtin_amdgcn_exp2f(x * 2.8853900817779268f);  // e^{2x}
    return 1.0f - 2.0f * __builtin_amdgcn_rcpf(e + 1.0f);
}

__device__ __forceinline__ int wave_argmax(float v) {
    float m = v;
#pragma unroll
    for (int off = 32; off; off >>= 1) {
        float o = __shfl_xor(m, off);
        m = fmaxf(m, o);
    }
    unsigned long long bal = __ballot(v == m);
    return __ffsll((unsigned long long)bal) - 1;
}

// ---------------- Kernel 1: subgraph selection (one WAVE per batch) ---------
// Block 0 additionally precomputes the conv1d bf16 weight fragments into d_ws
// (consumed by k_conv1d, which is stream-ordered after this kernel).
__global__ __launch_bounds__(256) void k_select(const float* __restrict__ att,
                                                const float* __restrict__ deg,
                                                float* __restrict__ out_idx,
                                                const float* __restrict__ w1d,
                                                unsigned short* __restrict__ wf, int B) {
    const int wid = threadIdx.x >> 6;
    const int lane = threadIdx.x & 63;
    const int b = blockIdx.x * 4 + wid;
    if (b < B) {
        float dv = (lane < SEQ) ? deg[(size_t)b * SEQ + lane] : -1e30f;
        const float* abase = att + (size_t)b * SEQ * SEQ;
        float* outp = out_idx + (size_t)b * (KG * MM);

        // top-8 of degree depends only on degree: compute all bi upfront...
        int bis[KG];
#pragma unroll
        for (int g = 0; g < KG; ++g) {
            int bi = wave_argmax(dv);
            if (lane == bi) dv = -1e30f;
            bis[g] = bi;
        }
        // ...then issue all 8 row loads together (latency overlapped)
        float rv[KG];
#pragma unroll
        for (int g = 0; g < KG; ++g)
            rv[g] = (lane < SEQ) ? abase[(size_t)bis[g] * SEQ + lane] : -1e30f;

        bool my_sel = (lane == SITE);
#pragma unroll
        for (int g = 0; g < KG; ++g) {
            float r = my_sel ? -1e30f : rv[g];
            unsigned long long grp = 0;
#pragma unroll
            for (int m = 0; m < MM; ++m) {
                int pi = wave_argmax(r);
                if (lane == pi) { r = -1e30f; my_sel = true; }
                grp |= 1ull << pi;
            }
            if (lane < MM) {
                unsigned long long gg = grp;
                for (int t = 0; t < lane; ++t) gg &= gg - 1;
                outp[g * MM + lane] = (float)(__ffsll((unsigned long long)gg) - 1);
            }
        }
    }

    // ---- folded weight-fragment precompute (block 0 only) ----
    if (blockIdx.x == 0) {
        for (int p = threadIdx.x; p < 18 * 64; p += 256) {
            int f = p >> 6, ln = p & 63;
            int k = f / 6, ks = (f / 3) % 2, mt = f % 3;
            int o = mt * 16 + (ln & 15);
#pragma unroll
            for (int j = 0; j < 8; ++j) {
                int i = ks * 32 + (ln >> 4) * 8 + j;
                float v = (o < SEQ && i < SEQ) ? w1d[(o * SEQ + i) * 3 + k] : 0.0f;
                wf[(size_t)p * 8 + j] = f2bf(v);
            }
        }
    }
}

// ---------------- Kernel 2: conv1d + double tanh via bf16 MFMA --------------
// Per wave (one batch), wave-private LDS, NO block barriers (round-4 skeleton).
// Staging vectorized: lane l (<41) owns x row l -> LDS row l+1 as 8 ds_write_b128
// (cols 0..40 packed bf16, 41..63 zero); lanes 41..49 zero rows {0,42..49}.
__global__ __launch_bounds__(256) void k_conv1d(const float* __restrict__ x,
                                                const bf16x8* __restrict__ wf,
                                                const float* __restrict__ b1d,
                                                float* __restrict__ out_site,
                                                float* __restrict__ out_asite, int B) {
    __shared__ __align__(16) unsigned short lds[4][ROWS * RST];
    const int tid = threadIdx.x;
    const int wid = tid >> 6;
    const int lane = tid & 63;
    const int b = blockIdx.x * 4 + wid;
    unsigned short* xb = lds[wid];

    const float* xp = x + (size_t)b * (SEQ * SEQ);

    if (lane < SEQ) {
        const float* rp = xp + lane * SEQ;
        unsigned short* rowp = xb + (lane + 1) * RST;
        u32x4 blk;
        {
            f32x4 v0 = ld4u(rp + 0), v1 = ld4u(rp + 4);
            blk[0] = pk2(v0[0], v0[1]); blk[1] = pk2(v0[2], v0[3]);
            blk[2] = pk2(v1[0], v1[1]); blk[3] = pk2(v1[2], v1[3]);
            *(u32x4*)(rowp + 0) = blk;
            f32x4 v2 = ld4u(rp + 8), v3 = ld4u(rp + 12);
            blk[0] = pk2(v2[0], v2[1]); blk[1] = pk2(v2[2], v2[3]);
            blk[2] = pk2(v3[0], v3[1]); blk[3] = pk2(v3[2], v3[3]);
            *(u32x4*)(rowp + 8) = blk;
        }
        {
            f32x4 v4 = ld4u(rp + 16), v5 = ld4u(rp + 20);
            blk[0] = pk2(v4[0], v4[1]); blk[1] = pk2(v4[2], v4[3]);
            blk[2] = pk2(v5[0], v5[1]); blk[3] = pk2(v5[2], v5[3]);
            *(u32x4*)(rowp + 16) = blk;
            f32x4 v6 = ld4u(rp + 24), v7 = ld4u(rp + 28);
            blk[0] = pk2(v6[0], v6[1]); blk[1] = pk2(v6[2], v6[3]);
            blk[2] = pk2(v7[0], v7[1]); blk[3] = pk2(v7[2], v7[3]);
            *(u32x4*)(rowp + 24) = blk;
        }
        {
            f32x4 v8 = ld4u(rp + 32), v9 = ld4u(rp + 36);
            float x40 = rp[40];
            blk[0] = pk2(v8[0], v8[1]); blk[1] = pk2(v8[2], v8[3]);
            blk[2] = pk2(v9[0], v9[1]); blk[3] = pk2(v9[2], v9[3]);
            *(u32x4*)(rowp + 32) = blk;
            blk[0] = pk2(x40, 0.0f); blk[1] = 0u; blk[2] = 0u; blk[3] = 0u;
            *(u32x4*)(rowp + 40) = blk;
            blk[0] = 0u;
            *(u32x4*)(rowp + 48) = blk;
            *(u32x4*)(rowp + 56) = blk;
        }
    } else {
        int z = lane - 41;          // 0..22
        if (z < 9) {                // rows {0, 42..49}
            int row = (z == 0) ? 0 : (41 + z);
            u32x4* rowp = (u32x4*)(xb + row * RST);
            const u32x4 zv = {0u, 0u, 0u, 0u};
#pragma unroll
            for (int c = 0; c < 8; ++c) rowp[c] = zv;
        }
    }

    // Asite: exact f32 copy of row 20 (L1-hot)
    if (lane < SEQ) out_asite[(size_t)b * SEQ + lane] = xp[SITE * SEQ + lane];

    // A fragments after staging (cuts peak VGPR; latency hidden by sibling waves)
    bf16x8 afr[18];
#pragma unroll
    for (int f = 0; f < 18; ++f) afr[f] = wf[f * 64 + lane];

    asm volatile("s_waitcnt lgkmcnt(0)" ::: "memory");

    const int h16 = lane & 15;
    const int kgrp = lane >> 4;

    f32x4 acc[3][3];
#pragma unroll
    for (int a = 0; a < 3; ++a)
#pragma unroll
        for (int n = 0; n < 3; ++n)
#pragma unroll
            for (int j = 0; j < 4; ++j) acc[a][n][j] = 0.0f;

#pragma unroll
    for (int k = 0; k < 3; ++k) {
#pragma unroll
        for (int ks = 0; ks < 2; ++ks) {
#pragma unroll
            for (int nt = 0; nt < 3; ++nt) {
                int c = nt * 16 + h16 + k;
                const bf16x8 bfrag = *(const bf16x8*)&xb[c * RST + (ks * 4 + kgrp) * 8];
#pragma unroll
                for (int mt = 0; mt < 3; ++mt)
                    acc[mt][nt] = __builtin_amdgcn_mfma_f32_16x16x32_bf16(
                        afr[(k * 2 + ks) * 3 + mt], bfrag, acc[mt][nt], 0, 0, 0);
            }
        }
    }

    // epilogue: +bias, double fast-tanh, predicated store
    float* outb = out_site + (size_t)b * (SEQ * SEQ);
#pragma unroll
    for (int mt = 0; mt < 3; ++mt) {
#pragma unroll
        for (int nt = 0; nt < 3; ++nt) {
            int h = nt * 16 + h16;
#pragma unroll
            for (int j = 0; j < 4; ++j) {
                int o = mt * 16 + kgrp * 4 + j;
                if (o < SEQ && h < SEQ) {
                    float v = acc[mt][nt][j] + b1d[o];
                    outb[o * SEQ + h] = fast_tanh(fast_tanh(v));
                }
            }
        }
    }
}

// ---------------- Kernel 3: gather + conv2d (block per batch) — unchanged ---
__global__ __launch_bounds__(256) void k_conv2d(const float* __restrict__ x,
                                                const float* __restrict__ w2,
                                                const float* __restrict__ b2,
                                                const float* __restrict__ idxf,
                                                float* __restrict__ out_bag, int B) {
    const int b = blockIdx.x;
    const int tid = threadIdx.x;
    __shared__ float ctx[KG][MM + 2][SEQ + 3];  // [8][7][44], zero border
    __shared__ int ridx[KG * MM];

    if (tid < KG * MM) ridx[tid] = (int)idxf[(size_t)b * KG * MM + tid];
    float* cz = &ctx[0][0][0];
    for (int t = tid; t < KG * (MM + 2) * (SEQ + 3); t += 256) cz[t] = 0.0f;
    __syncthreads();

    const float* xbp = x + (size_t)b * SEQ * SEQ;
    for (int t = tid; t < KG * MM * SEQ; t += 256) {
        int i = t / (MM * SEQ);
        int rem = t % (MM * SEQ);
        int m = rem / SEQ;
        int w = rem % SEQ;
        ctx[i][m + 1][w + 1] = xbp[ridx[i * MM + m] * SEQ + w];
    }
    __syncthreads();

    if (tid < MM * SEQ) {
        int m = tid / SEQ, w = tid % SEQ;
        float acc[KG];
#pragma unroll
        for (int o = 0; o < KG; ++o) acc[o] = b2[o];
#pragma unroll
        for (int i = 0; i < KG; ++i)
#pragma unroll
            for (int kh = 0; kh < 3; ++kh)
#pragma unroll
                for (int kw = 0; kw < 3; ++kw) {
                    float cv = ctx[i][m + kh][w + kw];
#pragma unroll
                    for (int o = 0; o < KG; ++o)
                        acc[o] += cv * w2[((o * KG + i) * 3 + kh) * 3 + kw];
                }
        size_t base = (size_t)b * KG * MM * SEQ + (size_t)m * SEQ + w;
#pragma unroll
        for (int o = 0; o < KG; ++o)
            out_bag[base + (size_t)o * MM * SEQ] = acc[o];
    }
}

extern "C" void kernel_launch(void* const* d_in, const int* in_sizes, int n_in,
                              void* d_out, int out_size, void* d_ws, size_t ws_size,
                              hipStream_t stream) {
    const float* att = (const float*)d_in[0];
    const float* deg = (const float*)d_in[1];
    const float* x   = (const float*)d_in[2];
    const float* w1d = (const float*)d_in[3];
    const float* b1d = (const float*)d_in[4];
    const float* w2d = (const float*)d_in[5];
    const float* b2d = (const float*)d_in[6];
    const int B = in_sizes[1] / SEQ;  // degree is [B, SEQ]

    float* out = (float*)d_out;
    const size_t s_bag   = (size_t)B * KG * MM * SEQ;  // x_bag  [B,8,5,41]
    const size_t s_asite = (size_t)B * SEQ;            // Asite  [B,1,41]
    const size_t s_site  = (size_t)B * SEQ * SEQ;      // x_site [B,41,41]
    float* o_bag   = out;
    float* o_asite = out + s_bag;
    float* o_site  = out + s_bag + s_asite;
    float* o_idx   = out + s_bag + s_asite + s_site;   // index_all as f32 [B,8,5]

    k_select<<<(B + 3) / 4, 256, 0, stream>>>(att, deg, o_idx, w1d,
                                              (unsigned short*)d_ws, B);
    k_conv1d<<<B / 4, 256, 0, stream>>>(x, (const bf16x8*)d_ws, b1d, o_site, o_asite, B);
    k_conv2d<<<B, 256, 0, stream>>>(x, w2d, b2d, o_idx, o_bag, B);
}